// Round 3
// baseline (552.273 us; speedup 1.0000x reference)
//
#include <hip/hip_runtime.h>
#include <hip/hip_bf16.h>
#include <cstddef>

#define B_SZ 1024
#define C_SZ 1000
#define H_SZ 768
#define K_SZ 128
#define MAXS 16     // bucket capacity per class (P(overflow) ~ 1e-10, uniform y)
#define CHUNK 4     // samples processed per slab stream

typedef __attribute__((ext_vector_type(8))) short bf16x8;
typedef __attribute__((ext_vector_type(4))) float f32x4;

// ws layout (bytes):
//   [0,        1572864)  : negx bf16 [B][H]   (relu(-x) pre-applied)
//   [1572864,  2752512)  : W    bf16 [H][H]
//   [4194304,  7340032)  : x1   fp32 [B][H]
//   [8388608,  8392608)  : counts int [C]
//   [8392704,  8456704)  : buckets int [C][MAXS]
#define WS_NEGX_OFF 0
#define WS_W_OFF    1572864
#define WS_X1_OFF   4194304
#define WS_CNT_OFF  8388608
#define WS_BKT_OFF  8392704

// ---------------------------------------------------------------------------
// Kernel 0: fused convert — negx = bf16(relu(-x)), Wb = bf16(W)
// ---------------------------------------------------------------------------
__global__ __launch_bounds__(256) void convert_pack(
    const float* __restrict__ x, const float* __restrict__ W,
    ushort* __restrict__ negx, ushort* __restrict__ Wb)
{
    const int NX = B_SZ * H_SZ / 4;
    const int NW = H_SZ * H_SZ / 4;
    int i = blockIdx.x * 256 + threadIdx.x;
    if (i < NX) {
        float4 v = ((const float4*)x)[i];
        union { ushort u[4]; ushort4 v4; } o;
        o.u[0] = __bfloat16_as_ushort(__float2bfloat16(fmaxf(-v.x, 0.f)));
        o.u[1] = __bfloat16_as_ushort(__float2bfloat16(fmaxf(-v.y, 0.f)));
        o.u[2] = __bfloat16_as_ushort(__float2bfloat16(fmaxf(-v.z, 0.f)));
        o.u[3] = __bfloat16_as_ushort(__float2bfloat16(fmaxf(-v.w, 0.f)));
        ((ushort4*)negx)[i] = o.v4;
    } else {
        int j = i - NX;
        if (j < NW) {
            float4 v = ((const float4*)W)[j];
            union { ushort u[4]; ushort4 v4; } o;
            o.u[0] = __bfloat16_as_ushort(__float2bfloat16(v.x));
            o.u[1] = __bfloat16_as_ushort(__float2bfloat16(v.y));
            o.u[2] = __bfloat16_as_ushort(__float2bfloat16(v.z));
            o.u[3] = __bfloat16_as_ushort(__float2bfloat16(v.w));
            ((ushort4*)Wb)[j] = o.v4;
        }
    }
}

// ---------------------------------------------------------------------------
// Kernel 1: x1 = tanh(negx @ W^T + bias) via mfma_f32_16x16x32_bf16
// ---------------------------------------------------------------------------
__global__ __launch_bounds__(256) void mfma_gemm_tanh(
    const ushort* __restrict__ A, const ushort* __restrict__ Bw,
    const float* __restrict__ bias, float* __restrict__ x1)
{
    const int LDA = 40;
    __shared__ ushort sA[64 * LDA];
    __shared__ ushort sB[64 * LDA];

    const int t    = threadIdx.x;
    const int wave = t >> 6;
    const int lane = t & 63;
    const int wm   = wave >> 1;
    const int wn   = wave & 1;
    const int m0   = blockIdx.y * 64;
    const int n0   = blockIdx.x * 64;

    const int lr = t >> 2;
    const int lc = (t & 3) * 8;

    f32x4 acc[2][2] = {};

    const int fr = lane & 15;
    const int fk = (lane >> 4) * 8;

    for (int k0 = 0; k0 < H_SZ; k0 += 32) {
        *(bf16x8*)(&sA[lr * LDA + lc]) =
            *(const bf16x8*)(&A[(size_t)(m0 + lr) * H_SZ + k0 + lc]);
        *(bf16x8*)(&sB[lr * LDA + lc]) =
            *(const bf16x8*)(&Bw[(size_t)(n0 + lr) * H_SZ + k0 + lc]);
        __syncthreads();

        #pragma unroll
        for (int fi = 0; fi < 2; ++fi) {
            bf16x8 af = *(const bf16x8*)(&sA[(wm * 32 + fi * 16 + fr) * LDA + fk]);
            #pragma unroll
            for (int fj = 0; fj < 2; ++fj) {
                bf16x8 bf = *(const bf16x8*)(&sB[(wn * 32 + fj * 16 + fr) * LDA + fk]);
                acc[fi][fj] = __builtin_amdgcn_mfma_f32_16x16x32_bf16(
                    af, bf, acc[fi][fj], 0, 0, 0);
            }
        }
        __syncthreads();
    }

    const int col   = lane & 15;
    const int rbase = (lane >> 4) * 4;
    #pragma unroll
    for (int fi = 0; fi < 2; ++fi) {
        #pragma unroll
        for (int fj = 0; fj < 2; ++fj) {
            const int n  = n0 + wn * 32 + fj * 16 + col;
            const float bv = bias[n];
            #pragma unroll
            for (int r = 0; r < 4; ++r) {
                const int m = m0 + wm * 32 + fi * 16 + rbase + r;
                x1[(size_t)m * H_SZ + n] = tanhf(acc[fi][fj][r] + bv);
            }
        }
    }
}

// ---------------------------------------------------------------------------
// Kernel 2a: zero class counters (ws is poisoned before every call)
// ---------------------------------------------------------------------------
__global__ __launch_bounds__(256) void init_counts(int* __restrict__ counts)
{
    for (int i = threadIdx.x; i < C_SZ; i += 256) counts[i] = 0;
}

// ---------------------------------------------------------------------------
// Kernel 2b: bucket samples by class
// ---------------------------------------------------------------------------
__global__ __launch_bounds__(256) void build_buckets(
    const int* __restrict__ y, int* __restrict__ counts,
    int* __restrict__ buckets)
{
    const int b = blockIdx.x * 256 + threadIdx.x;
    if (b < B_SZ) {
        const int cls  = y[b];
        const int slot = atomicAdd(&counts[cls], 1);
        if (slot < MAXS) buckets[cls * MAXS + slot] = b;
    }
}

// ---------------------------------------------------------------------------
// Kernel 3: deduped gather-dot. One block per class; stream the 384 KB slab
// once, apply to up to CHUNK samples at a time (x1 rows staged in LDS).
// logits[b][k] = sum_h x1[b][h] * CW[c][h][k]  for each b in bucket[c].
// ---------------------------------------------------------------------------
__global__ __launch_bounds__(256) void gather_dot_dedup(
    const float* __restrict__ x1, const int* __restrict__ counts,
    const int* __restrict__ buckets, const float* __restrict__ cw,
    float* __restrict__ out)
{
    const int c = blockIdx.x;
    int n = counts[c];
    if (n == 0) return;
    if (n > MAXS) n = MAXS;

    const int t  = threadIdx.x;
    const int k4 = t & 31;   // float4 lane along K
    const int hg = t >> 5;   // h group 0..7

    __shared__ float  sx[CHUNK][H_SZ];
    __shared__ float4 red[8][32];
    __shared__ int    sb[CHUNK];

    const float4* __restrict__ wrow =
        (const float4*)(cw + (size_t)c * H_SZ * K_SZ);

    for (int s0 = 0; s0 < n; s0 += CHUNK) {
        const int m = min(CHUNK, n - s0);
        if (t < m) sb[t] = buckets[c * MAXS + s0 + t];
        __syncthreads();
        for (int s = 0; s < m; ++s) {
            const int b = sb[s];
            for (int i = t; i < H_SZ; i += 256)
                sx[s][i] = x1[(size_t)b * H_SZ + i];
        }
        __syncthreads();

        float4 acc[CHUNK] = {};
        #pragma unroll 8
        for (int h = hg; h < H_SZ; h += 8) {
            const float4 w = wrow[h * 32 + k4];
            #pragma unroll
            for (int s = 0; s < CHUNK; ++s) {
                const float xv = sx[s][h];
                acc[s].x += xv * w.x;
                acc[s].y += xv * w.y;
                acc[s].z += xv * w.z;
                acc[s].w += xv * w.w;
            }
        }

        for (int s = 0; s < m; ++s) {
            red[hg][k4] = acc[s];
            __syncthreads();
            if (hg == 0) {
                float4 r = red[0][k4];
                #pragma unroll
                for (int g = 1; g < 8; ++g) {
                    float4 o = red[g][k4];
                    r.x += o.x; r.y += o.y; r.z += o.z; r.w += o.w;
                }
                ((float4*)out)[(size_t)sb[s] * 32 + k4] = r;
            }
            __syncthreads();
        }
    }
}

extern "C" void kernel_launch(void* const* d_in, const int* in_sizes, int n_in,
                              void* d_out, int out_size, void* d_ws, size_t ws_size,
                              hipStream_t stream) {
    const float* x    = (const float*)d_in[0];   // [B, H]
    const int*   y    = (const int*)  d_in[1];   // [B]
    const float* cw   = (const float*)d_in[2];   // [C, H, K]
    // d_in[3] = class_bias — unused by the reference math
    const float* Wlin = (const float*)d_in[4];   // [H, H]
    const float* blin = (const float*)d_in[5];   // [H]
    float* out = (float*)d_out;                  // [B, K]

    char* ws = (char*)d_ws;
    ushort* negx  = (ushort*)(ws + WS_NEGX_OFF);
    ushort* Wb    = (ushort*)(ws + WS_W_OFF);
    float*  x1    = (float*) (ws + WS_X1_OFF);
    int*    cnts  = (int*)   (ws + WS_CNT_OFF);
    int*    bkts  = (int*)   (ws + WS_BKT_OFF);

    const int total4 = (B_SZ * H_SZ + H_SZ * H_SZ) / 4;
    convert_pack<<<(total4 + 255) / 256, 256, 0, stream>>>(x, Wlin, negx, Wb);

    init_counts<<<1, 256, 0, stream>>>(cnts);
    build_buckets<<<B_SZ / 256, 256, 0, stream>>>(y, cnts, bkts);

    dim3 g1(H_SZ / 64, B_SZ / 64);
    mfma_gemm_tanh<<<g1, 256, 0, stream>>>(negx, Wb, blin, x1);

    gather_dot_dedup<<<C_SZ, 256, 0, stream>>>(x1, cnts, bkts, cw, out);
}

// Round 4
// 516.511 us; speedup vs baseline: 1.0692x; 1.0692x over previous
//
#include <hip/hip_runtime.h>
#include <hip/hip_bf16.h>
#include <cstddef>

#define B_SZ 1024
#define C_SZ 1000
#define H_SZ 768
#define K_SZ 128

typedef __attribute__((ext_vector_type(8))) short bf16x8;
typedef __attribute__((ext_vector_type(4))) float f32x4;

// ws layout (bytes):
//   [0,        1572864)  : negx bf16 [B][H]   (relu(-x) pre-applied)
//   [1572864,  2752512)  : W    bf16 [H][H]
//   [4194304,  7340032)  : x1   fp32 [B][H]
//   [8388608,  9437184)  : part fp32 [2][B][K]  (split-H partial logits)
#define WS_NEGX_OFF 0
#define WS_W_OFF    1572864
#define WS_X1_OFF   4194304
#define WS_PART_OFF 8388608

// ---------------------------------------------------------------------------
// Kernel 0: fused convert — negx = bf16(relu(-x)), Wb = bf16(W)
// ---------------------------------------------------------------------------
__global__ __launch_bounds__(256) void convert_pack(
    const float* __restrict__ x, const float* __restrict__ W,
    ushort* __restrict__ negx, ushort* __restrict__ Wb)
{
    const int NX = B_SZ * H_SZ / 4;
    const int NW = H_SZ * H_SZ / 4;
    int i = blockIdx.x * 256 + threadIdx.x;
    if (i < NX) {
        float4 v = ((const float4*)x)[i];
        union { ushort u[4]; ushort4 v4; } o;
        o.u[0] = __bfloat16_as_ushort(__float2bfloat16(fmaxf(-v.x, 0.f)));
        o.u[1] = __bfloat16_as_ushort(__float2bfloat16(fmaxf(-v.y, 0.f)));
        o.u[2] = __bfloat16_as_ushort(__float2bfloat16(fmaxf(-v.z, 0.f)));
        o.u[3] = __bfloat16_as_ushort(__float2bfloat16(fmaxf(-v.w, 0.f)));
        ((ushort4*)negx)[i] = o.v4;
    } else {
        int j = i - NX;
        if (j < NW) {
            float4 v = ((const float4*)W)[j];
            union { ushort u[4]; ushort4 v4; } o;
            o.u[0] = __bfloat16_as_ushort(__float2bfloat16(v.x));
            o.u[1] = __bfloat16_as_ushort(__float2bfloat16(v.y));
            o.u[2] = __bfloat16_as_ushort(__float2bfloat16(v.z));
            o.u[3] = __bfloat16_as_ushort(__float2bfloat16(v.w));
            ((ushort4*)Wb)[j] = o.v4;
        }
    }
}

// ---------------------------------------------------------------------------
// Kernel 1: x1 = tanh(negx @ W^T + bias) via mfma_f32_16x16x32_bf16
// ---------------------------------------------------------------------------
__global__ __launch_bounds__(256) void mfma_gemm_tanh(
    const ushort* __restrict__ A, const ushort* __restrict__ Bw,
    const float* __restrict__ bias, float* __restrict__ x1)
{
    const int LDA = 40;
    __shared__ ushort sA[64 * LDA];
    __shared__ ushort sB[64 * LDA];

    const int t    = threadIdx.x;
    const int wave = t >> 6;
    const int lane = t & 63;
    const int wm   = wave >> 1;
    const int wn   = wave & 1;
    const int m0   = blockIdx.y * 64;
    const int n0   = blockIdx.x * 64;

    const int lr = t >> 2;
    const int lc = (t & 3) * 8;

    f32x4 acc[2][2] = {};

    const int fr = lane & 15;
    const int fk = (lane >> 4) * 8;

    for (int k0 = 0; k0 < H_SZ; k0 += 32) {
        *(bf16x8*)(&sA[lr * LDA + lc]) =
            *(const bf16x8*)(&A[(size_t)(m0 + lr) * H_SZ + k0 + lc]);
        *(bf16x8*)(&sB[lr * LDA + lc]) =
            *(const bf16x8*)(&Bw[(size_t)(n0 + lr) * H_SZ + k0 + lc]);
        __syncthreads();

        #pragma unroll
        for (int fi = 0; fi < 2; ++fi) {
            bf16x8 af = *(const bf16x8*)(&sA[(wm * 32 + fi * 16 + fr) * LDA + fk]);
            #pragma unroll
            for (int fj = 0; fj < 2; ++fj) {
                bf16x8 bf = *(const bf16x8*)(&sB[(wn * 32 + fj * 16 + fr) * LDA + fk]);
                acc[fi][fj] = __builtin_amdgcn_mfma_f32_16x16x32_bf16(
                    af, bf, acc[fi][fj], 0, 0, 0);
            }
        }
        __syncthreads();
    }

    const int col   = lane & 15;
    const int rbase = (lane >> 4) * 4;
    #pragma unroll
    for (int fi = 0; fi < 2; ++fi) {
        #pragma unroll
        for (int fj = 0; fj < 2; ++fj) {
            const int n  = n0 + wn * 32 + fj * 16 + col;
            const float bv = bias[n];
            #pragma unroll
            for (int r = 0; r < 4; ++r) {
                const int m = m0 + wm * 32 + fi * 16 + rbase + r;
                x1[(size_t)m * H_SZ + n] = tanhf(acc[fi][fj][r] + bv);
            }
        }
    }
}

// ---------------------------------------------------------------------------
// Kernel 2: split-H gather-dot.
// Grid (B, 2): block (b, half) computes part[half][b][k] =
//   sum_{h in half} x1[b][h] * CW[y[b]][h][k]
// 2048 blocks (8/CU) — 2x the memory-level parallelism of the 1024-block
// version; per-block stream is 192 KB contiguous (in 4 KB block-iterations).
// ---------------------------------------------------------------------------
__global__ __launch_bounds__(256) void gather_dot_split(
    const float* __restrict__ x1, const int* __restrict__ y,
    const float* __restrict__ cw, float* __restrict__ part)
{
    const int HH   = H_SZ / 2;          // 384
    const int b    = blockIdx.x;
    const int half = blockIdx.y;
    const int t    = threadIdx.x;
    const int k4   = t & 31;            // float4 lane along K
    const int hg   = t >> 5;            // h group 0..7
    const int h0   = half * HH;

    __shared__ float  sx[HH];
    __shared__ float4 red[8][32];

    const int cls = y[b];
    const float4* __restrict__ wrow =
        (const float4*)(cw + (size_t)cls * H_SZ * K_SZ) + (size_t)h0 * 32;

    for (int i = t; i < HH; i += 256)
        sx[i] = x1[(size_t)b * H_SZ + h0 + i];
    __syncthreads();

    float4 acc = {0.f, 0.f, 0.f, 0.f};
    #pragma unroll 8
    for (int h = hg; h < HH; h += 8) {
        const float  xv = sx[h];
        const float4 w  = wrow[h * 32 + k4];
        acc.x += xv * w.x;
        acc.y += xv * w.y;
        acc.z += xv * w.z;
        acc.w += xv * w.w;
    }

    red[hg][k4] = acc;
    __syncthreads();
    if (hg == 0) {
        float4 r = red[0][k4];
        #pragma unroll
        for (int g = 1; g < 8; ++g) {
            float4 o = red[g][k4];
            r.x += o.x; r.y += o.y; r.z += o.z; r.w += o.w;
        }
        ((float4*)part)[((size_t)half * B_SZ + b) * 32 + k4] = r;
    }
}

// ---------------------------------------------------------------------------
// Kernel 3: combine halves — out = part[0] + part[1]
// ---------------------------------------------------------------------------
__global__ __launch_bounds__(256) void combine_halves(
    const float* __restrict__ part, float* __restrict__ out)
{
    const int N4 = B_SZ * K_SZ / 4;     // 32768 float4
    int i = blockIdx.x * 256 + threadIdx.x;
    if (i < N4) {
        float4 a = ((const float4*)part)[i];
        float4 b = ((const float4*)part)[N4 + i];
        float4 r = {a.x + b.x, a.y + b.y, a.z + b.z, a.w + b.w};
        ((float4*)out)[i] = r;
    }
}

extern "C" void kernel_launch(void* const* d_in, const int* in_sizes, int n_in,
                              void* d_out, int out_size, void* d_ws, size_t ws_size,
                              hipStream_t stream) {
    const float* x    = (const float*)d_in[0];   // [B, H]
    const int*   y    = (const int*)  d_in[1];   // [B]
    const float* cw   = (const float*)d_in[2];   // [C, H, K]
    // d_in[3] = class_bias — unused by the reference math
    const float* Wlin = (const float*)d_in[4];   // [H, H]
    const float* blin = (const float*)d_in[5];   // [H]
    float* out = (float*)d_out;                  // [B, K]

    char* ws = (char*)d_ws;
    ushort* negx = (ushort*)(ws + WS_NEGX_OFF);
    ushort* Wb   = (ushort*)(ws + WS_W_OFF);
    float*  x1   = (float*) (ws + WS_X1_OFF);
    float*  part = (float*) (ws + WS_PART_OFF);

    const int total4 = (B_SZ * H_SZ + H_SZ * H_SZ) / 4;
    convert_pack<<<(total4 + 255) / 256, 256, 0, stream>>>(x, Wlin, negx, Wb);

    dim3 g1(H_SZ / 64, B_SZ / 64);               // 12 x 16 = 192 blocks
    mfma_gemm_tanh<<<g1, 256, 0, stream>>>(negx, Wb, blin, x1);

    dim3 g2(B_SZ, 2);                            // 2048 blocks
    gather_dot_split<<<g2, 256, 0, stream>>>(x1, y, cw, part);

    combine_halves<<<(B_SZ * K_SZ / 4 + 255) / 256, 256, 0, stream>>>(part, out);
}